// Round 17
// baseline (268.214 us; speedup 1.0000x reference)
//
#include <hip/hip_runtime.h>
#include <hip/hip_bf16.h>

typedef __attribute__((ext_vector_type(8))) short bf16x8;
typedef __attribute__((ext_vector_type(4))) float f32x4;
typedef __attribute__((ext_vector_type(16))) float f32x16;
typedef unsigned short u16;
typedef unsigned int u32;

#define DEV static __device__ __forceinline__

DEV u16 f2us(float x) {
  __hip_bfloat16 h = __float2bfloat16(x);
  union { __hip_bfloat16 h; u16 u; } c; c.h = h; return c.u;
}
DEV float us2f(u16 u) {
  union { __hip_bfloat16 h; u16 u; } c; c.u = u;
  return __bfloat162float(c.h);
}
DEV f32x16 mfma32(bf16x8 a, bf16x8 b, f32x16 c) {
  return __builtin_amdgcn_mfma_f32_32x32x16_bf16(a, b, c, 0, 0, 0);
}
// pack two f32 -> u32 of two bf16 (RNE)
DEV u32 pkbf(float a, float b) {
  return (u32)f2us(a) | ((u32)f2us(b) << 16);
}
// async global->LDS, 16B per lane (dest = wave-uniform base + lane*16)
DEV void gl16(const u16* g, u16* l) {
  __builtin_amdgcn_global_load_lds(
      (const __attribute__((address_space(1))) unsigned int*)(g),
      (__attribute__((address_space(3))) unsigned int*)(l), 16, 0, 0);
}

// ---------------- problem constants ----------------
// B=2, L=2048, D=1024, H=16, DH=64, P=L+1=2049
constexpr int PE_ROWS = 2144;   // 2048 + 96 band pad (max row read = 2143)
constexpr int PE_M    = 2176;   // 17 * 128 (GEMM M for PE)
constexpr float QSCALE = 0.125f; // folded softmax scale (dh^-0.5)

// ---------------- workspace layout (bytes) ----------------
constexpr size_t SZ_QKV  = (size_t)4096 * 1024 * 2;
constexpr size_t SZ_W    = (size_t)1024 * 1024 * 2;
constexpr size_t SZ_POSB = (size_t)PE_M * 1024 * 2;
constexpr size_t OFF_QB   = 0;
constexpr size_t OFF_KB   = OFF_QB  + SZ_QKV;
constexpr size_t OFF_VB   = OFF_KB  + SZ_QKV;
constexpr size_t OFF_WQT  = OFF_VB  + SZ_QKV;
constexpr size_t OFF_WKT  = OFF_WQT + SZ_W;
constexpr size_t OFF_WVT  = OFF_WKT + SZ_W;
constexpr size_t OFF_WOT  = OFF_WVT + SZ_W;
constexpr size_t OFF_RKT  = OFF_WOT + SZ_W;
constexpr size_t OFF_POSB = OFF_RKT + SZ_W;
constexpr size_t OFF_QW   = OFF_POSB + SZ_POSB;
constexpr size_t OFF_QR   = OFF_QW  + SZ_QKV;
constexpr size_t OFF_KH   = OFF_QR  + SZ_QKV;
constexpr size_t OFF_VT   = OFF_KH  + SZ_QKV;
constexpr size_t OFF_PEH  = OFF_VT  + SZ_QKV;
constexpr size_t OFF_ATTNB = OFF_QB;  // alias: qb dead after Q-projection GEMM

// ---------------- fused prep kernel (f2b + W transpose + rk transpose) -------
struct PrepPtrs {
  const float4 *q, *k, *v, *pos;
  u16 *qb, *kb, *vb, *posb;
  const float *Wq, *Wk, *Wv, *Wo, *rk;
  u16 *Wqt, *Wkt, *Wvt, *Wot, *Rkt;
};

__global__ __launch_bounds__(256)
void k_prep(PrepPtrs P)
{
  __shared__ float t[32][33];
  const int bid = blockIdx.x;
  if (bid < 14464) {
    // fp32 -> bf16: q/k/v 4096 blocks each, pos 2176 (zero-fill tail)
    const float4* src; u16* dst; int i, n4in, n4tot;
    if (bid < 4096)       { src = P.q;   dst = P.qb;   i = bid * 256 + threadIdx.x;           n4in = 1048576; n4tot = 1048576; }
    else if (bid < 8192)  { src = P.k;   dst = P.kb;   i = (bid - 4096) * 256 + threadIdx.x;  n4in = 1048576; n4tot = 1048576; }
    else if (bid < 12288) { src = P.v;   dst = P.vb;   i = (bid - 8192) * 256 + threadIdx.x;  n4in = 1048576; n4tot = 1048576; }
    else                  { src = P.pos; dst = P.posb; i = (bid - 12288) * 256 + threadIdx.x; n4in = 524544;  n4tot = 557056; }
    if (i >= n4tot) return;
    float4 val;
    if (i < n4in) val = src[i];
    else { val.x = val.y = val.z = val.w = 0.f; }
    ushort4 o;
    o.x = f2us(val.x); o.y = f2us(val.y); o.z = f2us(val.z); o.w = f2us(val.w);
    *reinterpret_cast<ushort4*>(dst + (size_t)i * 4) = o;
    return;
  }
  const int tx = threadIdx.x & 31, ty = threadIdx.x >> 5;
  if (bid < 18560) {
    // W [1024][1024] -> Wt (transposed bf16); 1024 tiles per matrix
    const int tt = bid - 14464;
    const int z = tt >> 10, rr = tt & 1023;
    const float* in = (z == 0) ? P.Wq : (z == 1) ? P.Wk : (z == 2) ? P.Wv : P.Wo;
    u16* out = (z == 0) ? P.Wqt : (z == 1) ? P.Wkt : (z == 2) ? P.Wvt : P.Wot;
    const int kb0 = (rr & 31) * 32, nb0 = (rr >> 5) * 32;
#pragma unroll
    for (int r = 0; r < 32; r += 8)
      t[ty + r][tx] = in[(size_t)(kb0 + ty + r) * 1024 + nb0 + tx];
    __syncthreads();
#pragma unroll
    for (int r = 0; r < 32; r += 8)
      out[(size_t)(nb0 + ty + r) * 1024 + kb0 + tx] = f2us(t[tx][ty + r]);
    return;
  }
  {
    // r_kernel [16][1024][64] -> Rkt[(h*64+e)][d]
    const int tt = bid - 18560;
    const int e = tt & 1, d = (tt >> 1) & 31, h = tt >> 6;
    const int eb0 = e * 32, db0 = d * 32;
#pragma unroll
    for (int r = 0; r < 32; r += 8)
      t[ty + r][tx] = P.rk[(size_t)h * 65536 + (size_t)(db0 + ty + r) * 64 + eb0 + tx];
    __syncthreads();
#pragma unroll
    for (int r = 0; r < 32; r += 8)
      P.Rkt[(size_t)(h * 64 + eb0 + ty + r) * 1024 + db0 + tx] = f2us(t[tx][ty + r]);
  }
}

// ---------------- fused Q/K/V/PE projection GEMM ----------------
struct ProjPtrs {
  const u16 *A0, *A1, *A2, *A3;
  const u16 *B0, *B1, *B2, *B3;
  const float *bias0, *bias1, *bias2;
  const float *rwb, *rrb;
  u16 *Qw, *Qr, *Kh, *Vt, *PEh;
};

__global__ __launch_bounds__(256)
void k_gemm_proj(ProjPtrs pp)
{
  const int z = blockIdx.z;
  if (z == 3 && blockIdx.y >= PE_M / 128) return;
  const u16* A  = (z == 0) ? pp.A0 : (z == 1) ? pp.A1 : (z == 2) ? pp.A2 : pp.A3;
  const u16* Bt = (z == 0) ? pp.B0 : (z == 1) ? pp.B1 : (z == 2) ? pp.B2 : pp.B3;

  __shared__ __attribute__((aligned(16))) u16 As[128 * 32];
  __shared__ __attribute__((aligned(16))) u16 Bs[128 * 32];
  const int tid  = threadIdx.x;
  const int lane = tid & 63;
  const int wave = tid >> 6;
  const int bm = blockIdx.y * 128;
  const int bn = blockIdx.x * 128;
  const int wr = (wave >> 1) * 64;
  const int wc = (wave & 1) * 64;
  const int fr = lane & 15;
  const int fk = (lane >> 4) * 8;

  f32x4 zero = {0.f, 0.f, 0.f, 0.f};
  f32x4 acc[4][4];
#pragma unroll
  for (int m = 0; m < 4; ++m)
#pragma unroll
    for (int n = 0; n < 4; ++n) acc[m][n] = zero;

  const int cA = wave * 2;
  const u16* gA = A  + (size_t)(bm + cA * 16 + (lane >> 2)) * 1024 + (lane & 3) * 8;
  const u16* gB = Bt + (size_t)(bn + cA * 16 + (lane >> 2)) * 1024 + (lane & 3) * 8;
  u16* lA = As + cA * 512;
  u16* lB = Bs + cA * 512;

  for (int k0 = 0; k0 < 1024; k0 += 32) {
    gl16(gA + k0, lA);
    gl16(gA + 16 * 1024 + k0, lA + 512);
    gl16(gB + k0, lB);
    gl16(gB + 16 * 1024 + k0, lB + 512);
    __syncthreads();
    bf16x8 af[4], bfv[4];
#pragma unroll
    for (int m = 0; m < 4; ++m) af[m]  = *(const bf16x8*)(&As[(wr + m * 16 + fr) * 32 + fk]);
#pragma unroll
    for (int n = 0; n < 4; ++n) bfv[n] = *(const bf16x8*)(&Bs[(wc + n * 16 + fr) * 32 + fk]);
#pragma unroll
    for (int m = 0; m < 4; ++m)
#pragma unroll
      for (int n = 0; n < 4; ++n)
        acc[m][n] = __builtin_amdgcn_mfma_f32_16x16x32_bf16(af[m], bfv[n], acc[m][n], 0, 0, 0);
    __syncthreads();
  }

#pragma unroll
  for (int m = 0; m < 4; ++m)
#pragma unroll
    for (int n = 0; n < 4; ++n)
#pragma unroll
      for (int r = 0; r < 4; ++r) {
        const int grow = bm + wr + m * 16 + (lane >> 4) * 4 + r;
        const int gcol = bn + wc + n * 16 + fr;
        float v = acc[m][n][r];
        const int b_ = grow >> 11, l_ = grow & 2047;
        const int h_ = gcol >> 6,  e_ = gcol & 63;
        if (z == 0) {
          v += pp.bias0[gcol];
          const size_t o = (((size_t)(b_ * 16 + h_) * 2048 + l_) << 6) + e_;
          pp.Qw[o] = f2us((v + pp.rwb[gcol]) * QSCALE);
          pp.Qr[o] = f2us((v + pp.rrb[gcol]) * QSCALE);
        } else if (z == 1) {
          v += pp.bias1[gcol];
          const size_t o = (((size_t)(b_ * 16 + h_) * 2048 + l_) << 6) + e_;
          pp.Kh[o] = f2us(v);
        } else if (z == 2) {
          v += pp.bias2[gcol];
          const size_t o = (((size_t)(b_ * 16 + h_) * 64 + e_) << 11) + l_;
          pp.Vt[o] = f2us(v);
        } else {
          if (grow < PE_ROWS) {
            const size_t o = ((size_t)h_ * PE_ROWS + grow) * 64 + e_;
            pp.PEh[o] = f2us(v);
          }
        }
      }
}

// ---------------- output projection GEMM (fp32 out) ----------------
__global__ __launch_bounds__(256)
void k_gemm_o(const u16* __restrict__ A, const u16* __restrict__ Bt,
              const float* __restrict__ bias, float* __restrict__ outf)
{
  __shared__ __attribute__((aligned(16))) u16 As[128 * 32];
  __shared__ __attribute__((aligned(16))) u16 Bs[128 * 32];
  const int tid  = threadIdx.x;
  const int lane = tid & 63;
  const int wave = tid >> 6;
  const int bm = blockIdx.y * 128;
  const int bn = blockIdx.x * 128;
  const int wr = (wave >> 1) * 64;
  const int wc = (wave & 1) * 64;
  const int fr = lane & 15;
  const int fk = (lane >> 4) * 8;

  f32x4 zero = {0.f, 0.f, 0.f, 0.f};
  f32x4 acc[4][4];
#pragma unroll
  for (int m = 0; m < 4; ++m)
#pragma unroll
    for (int n = 0; n < 4; ++n) acc[m][n] = zero;

  const int cA = wave * 2;
  const u16* gA = A  + (size_t)(bm + cA * 16 + (lane >> 2)) * 1024 + (lane & 3) * 8;
  const u16* gB = Bt + (size_t)(bn + cA * 16 + (lane >> 2)) * 1024 + (lane & 3) * 8;
  u16* lA = As + cA * 512;
  u16* lB = Bs + cA * 512;

  for (int k0 = 0; k0 < 1024; k0 += 32) {
    gl16(gA + k0, lA);
    gl16(gA + 16 * 1024 + k0, lA + 512);
    gl16(gB + k0, lB);
    gl16(gB + 16 * 1024 + k0, lB + 512);
    __syncthreads();
    bf16x8 af[4], bfv[4];
#pragma unroll
    for (int m = 0; m < 4; ++m) af[m]  = *(const bf16x8*)(&As[(wr + m * 16 + fr) * 32 + fk]);
#pragma unroll
    for (int n = 0; n < 4; ++n) bfv[n] = *(const bf16x8*)(&Bs[(wc + n * 16 + fr) * 32 + fk]);
#pragma unroll
    for (int m = 0; m < 4; ++m)
#pragma unroll
      for (int n = 0; n < 4; ++n)
        acc[m][n] = __builtin_amdgcn_mfma_f32_16x16x32_bf16(af[m], bfv[n], acc[m][n], 0, 0, 0);
    __syncthreads();
  }

#pragma unroll
  for (int m = 0; m < 4; ++m)
#pragma unroll
    for (int n = 0; n < 4; ++n)
#pragma unroll
      for (int r = 0; r < 4; ++r) {
        const int grow = bm + wr + m * 16 + (lane >> 4) * 4 + r;
        const int gcol = bn + wc + n * 16 + fr;
        outf[(size_t)grow * 1024 + gcol] = acc[m][n][r] + bias[gcol];
      }
}

// ---------------- fused rel-position causal attention (shared-KV LDS) --------
// grid 512: block = 4 q-tiles {2j,2j+1,62-2j,63-2j} of one (h,b); all waves
// share the kv walk (uniform NST=32-j barrier loop; short waves idle-skip
// compute). K/V staged per 64-kv tile into LDS via gl16 (pre-swizzled source,
// linear dest; XOR cblk^= row&7), double-buffered m97-style (stage t+1, compute
// t, barrier). Each wave owns its full tile -> no merge, direct output write.

// stage K/V tile for step STV into buffer BB (all 4 waves, 4 gl16 each)
#define STAGE(STV, BB)                                                         \
  {                                                                            \
    const int c0s_ = (STV) * 64;                                               \
    _Pragma("unroll")                                                          \
    for (int cc = 0; cc < 2; ++cc) {                                           \
      const int Pu = cc * 256 + wave * 64 + lane;                              \
      const int ru = Pu >> 3;                                                  \
      const int cbu = (Pu & 7) ^ (ru & 7);                                     \
      gl16(K_h + (size_t)(c0s_ + ru) * 64 + cbu * 8,                           \
           &KS[BB][(cc * 256 + wave * 64) * 8]);                               \
      gl16(V_h + (size_t)ru * 2048 + c0s_ + cbu * 8,                           \
           &VS[BB][(cc * 256 + wave * 64) * 8]);                               \
    }                                                                          \
  }

// PV update for one 32-kv half (V from LDS, swizzled)
#define PV_HALF(WARR, KT, BB)                                                  \
  {                                                                            \
    _Pragma("unroll")                                                          \
    for (int kvs = 0; kvs < 2; ++kvs) {                                        \
      u32 snd0 = hi ? WARR[4 * kvs]     : WARR[4 * kvs + 2];                   \
      u32 snd1 = hi ? WARR[4 * kvs + 1] : WARR[4 * kvs + 3];                   \
      u32 r0 = (u32)__shfl_xor((int)snd0, 32);                                 \
      u32 r1 = (u32)__shfl_xor((int)snd1, 32);                                 \
      union { u32 u[4]; bf16x8 v; } pf;                                        \
      pf.u[0] = hi ? r0 : WARR[4 * kvs];                                       \
      pf.u[1] = hi ? r1 : WARR[4 * kvs + 1];                                   \
      pf.u[2] = hi ? WARR[4 * kvs + 2] : r0;                                   \
      pf.u[3] = hi ? WARR[4 * kvs + 3] : r1;                                   \
      const int cbv_ = ((KT) * 4 + kvs * 2 + hi) ^ (l31 & 7);                  \
      bf16x8 v0_ = *(const bf16x8*)(&VS[BB][l31 * 64 + cbv_ * 8]);             \
      bf16x8 v1_ = *(const bf16x8*)(&VS[BB][(32 + l31) * 64 + cbv_ * 8]);      \
      Oc0 = mfma32(v0_, pf.v, Oc0);                                            \
      Oc1 = mfma32(v1_, pf.v, Oc1);                                            \
    }                                                                          \
  }

// one 32-kv half at tile origin q0 (K from LDS, swizzled)
#define ATTN_HALF(c0_, KT, BB)                                                 \
  {                                                                            \
    const int c0h_ = (c0_) + (KT) * 32;                                        \
    f32x16 sv_ = {};                                                           \
    {                                                                          \
      const int rk_ = (KT) * 32 + l31;                                         \
      bf16x8 qwf_[4], kf_[4];                                                  \
      _Pragma("unroll")                                                        \
      for (int kk = 0; kk < 4; ++kk) {                                         \
        qwf_[kk] = *(const bf16x8*)(Qw_h + (size_t)(q0 + l31) * 64             \
                                    + kk * 16 + hi * 8);                       \
        const int cbk_ = (kk * 2 + hi) ^ (rk_ & 7);                            \
        kf_[kk] = *(const bf16x8*)(&KS[BB][rk_ * 64 + cbk_ * 8]);              \
      }                                                                        \
      _Pragma("unroll")                                                        \
      for (int kk = 0; kk < 4; ++kk) sv_ = mfma32(kf_[kk], qwf_[kk], sv_);     \
    }                                                                          \
    _Pragma("unroll")                                                          \
    for (int r = 0; r < 16; ++r) {                                             \
      const int pat = (r & 3) + 8 * (r >> 2) + 4 * hi;                         \
      float x = sv_[r] + us2f(Ew[l31][(KT) * 32 + pat + 31 - l31]);            \
      if (c0h_ + pat > q0 + l31) x = -1e30f;                                   \
      sv_[r] = x;                                                              \
    }                                                                          \
    float mx_ = sv_[0];                                                        \
    _Pragma("unroll")                                                          \
    for (int r = 1; r < 16; ++r) mx_ = fmaxf(mx_, sv_[r]);                     \
    mx_ = fmaxf(mx_, __shfl_xor(mx_, 32));                                     \
    const float mn_ = fmaxf(mrun, mx_);                                        \
    const float al_ = __expf(mrun - mn_);                                      \
    mrun = mn_;                                                                \
    float rsum_ = 0.f;                                                         \
    u32 wa_[8];                                                                \
    _Pragma("unroll")                                                          \
    for (int g8 = 0; g8 < 8; ++g8) {                                           \
      float pa_ = __expf(sv_[2 * g8] - mn_);                                   \
      float pb_ = __expf(sv_[2 * g8 + 1] - mn_);                               \
      u16 ua_ = f2us(pa_), ub_ = f2us(pb_);                                    \
      rsum_ += us2f(ua_) + us2f(ub_);                                          \
      wa_[g8] = (u32)ua_ | ((u32)ub_ << 16);                                   \
    }                                                                          \
    ls = ls * al_ + rsum_ + __shfl_xor(rsum_, 32);                             \
    Oc0 *= al_;                                                                \
    Oc1 *= al_;                                                                \
    PV_HALF(wa_, KT, BB)                                                       \
  }

// one 64-kv step: E band (3 tiles, global PE, step-scoped qrf), then 2 halves
#define ATTN_STEP(stv, BB)                                                     \
  {                                                                            \
    const int c0_ = (stv) * 64;                                                \
    const int Jb_ = 2048 + c0_ - q0 - 31;                                      \
    {                                                                          \
      bf16x8 qrf_[4];                                                          \
      _Pragma("unroll")                                                        \
      for (int kk = 0; kk < 4; ++kk)                                           \
        qrf_[kk] = *(const bf16x8*)(Qr_h + (size_t)(q0 + l31) * 64             \
                                    + kk * 16 + hi * 8);                       \
      _Pragma("unroll")                                                        \
      for (int tau = 0; tau < 3; ++tau) {                                      \
        f32x16 e_ = {};                                                        \
        {                                                                      \
          bf16x8 pe_[4];                                                       \
          _Pragma("unroll")                                                    \
          for (int kk = 0; kk < 4; ++kk)                                       \
            pe_[kk] = *(const bf16x8*)(PE_h + (size_t)(Jb_ + tau * 32 + l31)   \
                                       * 64 + kk * 16 + hi * 8);               \
          _Pragma("unroll")                                                    \
          for (int kk = 0; kk < 4; ++kk) e_ = mfma32(pe_[kk], qrf_[kk], e_);   \
        }                                                                      \
        _Pragma("unroll")                                                      \
        for (int g4 = 0; g4 < 4; ++g4) {                                       \
          uint2 w2_;                                                           \
          w2_.x = pkbf(e_[4 * g4 + 0], e_[4 * g4 + 1]);                        \
          w2_.y = pkbf(e_[4 * g4 + 2], e_[4 * g4 + 3]);                        \
          *(uint2*)(&Ew[l31][tau * 32 + 8 * g4 + 4 * hi]) = w2_;               \
        }                                                                      \
      }                                                                        \
    }                                                                          \
    ATTN_HALF(c0_, 0, BB)                                                      \
    ATTN_HALF(c0_, 1, BB)                                                      \
  }

__global__ __launch_bounds__(256, 2)
void k_attn(const u16* __restrict__ Qw, const u16* __restrict__ Qr,
            const u16* __restrict__ Kh, const u16* __restrict__ Vt,
            const u16* __restrict__ PEh, u16* __restrict__ attnb)
{
  const int bid = blockIdx.x;                 // 512 blocks
  const int xcd = bid & 7, s = bid >> 3;      // s in [0,64)
  const int j = s & 15, g = s >> 4;           // j tile-group, g in [0,4)
  const int hb = xcd + 8 * g;
  const int h = hb & 15, b = hb >> 4;
  const int wave = threadIdx.x >> 6, lane = threadIdx.x & 63;
  const int l31 = lane & 31, hi = lane >> 5;

  const int qt = (wave == 0) ? 2 * j : (wave == 1) ? 2 * j + 1
               : (wave == 2) ? 62 - 2 * j : 63 - 2 * j;
  const int q0 = qt * 32;
  const int nst = qt / 2 + 1;                 // this wave's active steps
  const int NST = 32 - j;                     // block step count (= max nst)

  const u16* Qw_h = Qw + (size_t)hb * (2048 * 64);
  const u16* Qr_h = Qr + (size_t)hb * (2048 * 64);
  const u16* K_h  = Kh + (size_t)hb * (2048 * 64);
  const u16* V_h  = Vt + (size_t)hb * (64 * 2048);
  const u16* PE_h = PEh + (size_t)h * (PE_ROWS * 64);

  __shared__ __attribute__((aligned(16))) u16 KS[2][4096];   // [64][8 u16x8] sw
  __shared__ __attribute__((aligned(16))) u16 VS[2][4096];
  __shared__ __attribute__((aligned(16))) u16 Elds_all[4][32][100];
  u16 (*Ew)[100] = Elds_all[wave];

  f32x16 Oc0 = {}, Oc1 = {};
  float mrun = -1e30f, ls = 0.f;

  // prologue: stage tile 0
  STAGE(0, 0)
  __syncthreads();

  int bb = 0;
  for (int st = 0; st < NST; ++st) {
    if (st + 1 < NST) STAGE(st + 1, bb ^ 1)
    if (st < nst) ATTN_STEP(st, bb)
    __syncthreads();
    bb ^= 1;
  }

  // epilogue: direct per-wave output write (row q0+l31, cols h*64 + d)
  const float inv = 1.f / ls;
  const size_t orow = ((size_t)(b * 2048 + q0 + l31)) * 1024 + h * 64;
#pragma unroll
  for (int g4 = 0; g4 < 4; ++g4) {
    const int d = 8 * g4 + 4 * hi;
    ushort4 s0;
    s0.x = f2us(Oc0[4 * g4 + 0] * inv);
    s0.y = f2us(Oc0[4 * g4 + 1] * inv);
    s0.z = f2us(Oc0[4 * g4 + 2] * inv);
    s0.w = f2us(Oc0[4 * g4 + 3] * inv);
    *(ushort4*)(attnb + orow + d) = s0;
    ushort4 s1;
    s1.x = f2us(Oc1[4 * g4 + 0] * inv);
    s1.y = f2us(Oc1[4 * g4 + 1] * inv);
    s1.z = f2us(Oc1[4 * g4 + 2] * inv);
    s1.w = f2us(Oc1[4 * g4 + 3] * inv);
    *(ushort4*)(attnb + orow + 32 + d) = s1;
  }
}

// ---------------- launch ----------------
extern "C" void kernel_launch(void* const* d_in, const int* in_sizes, int n_in,
                              void* d_out, int out_size, void* d_ws, size_t ws_size,
                              hipStream_t stream)
{
  const float* q   = (const float*)d_in[0];
  const float* k   = (const float*)d_in[1];
  const float* v   = (const float*)d_in[2];
  const float* pos = (const float*)d_in[3];
  const float* Wq  = (const float*)d_in[4];
  const float* bq  = (const float*)d_in[5];
  const float* Wk  = (const float*)d_in[6];
  const float* bk  = (const float*)d_in[7];
  const float* Wv  = (const float*)d_in[8];
  const float* bv  = (const float*)d_in[9];
  const float* Wo  = (const float*)d_in[10];
  const float* bo  = (const float*)d_in[11];
  const float* rwb = (const float*)d_in[12];
  const float* rrb = (const float*)d_in[13];
  const float* rk  = (const float*)d_in[14];

  char* ws = (char*)d_ws;
  u16* qb    = (u16*)(ws + OFF_QB);
  u16* kb    = (u16*)(ws + OFF_KB);
  u16* vb    = (u16*)(ws + OFF_VB);
  u16* Wqt   = (u16*)(ws + OFF_WQT);
  u16* Wkt   = (u16*)(ws + OFF_WKT);
  u16* Wvt   = (u16*)(ws + OFF_WVT);
  u16* Wot   = (u16*)(ws + OFF_WOT);
  u16* Rkt   = (u16*)(ws + OFF_RKT);
  u16* posb  = (u16*)(ws + OFF_POSB);
  u16* Qw    = (u16*)(ws + OFF_QW);
  u16* Qr    = (u16*)(ws + OFF_QR);
  u16* Kh    = (u16*)(ws + OFF_KH);
  u16* Vt    = (u16*)(ws + OFF_VT);
  u16* PEh   = (u16*)(ws + OFF_PEH);
  u16* attnb = (u16*)(ws + OFF_ATTNB);
  float* outf = (float*)d_out;

  // fused prep (1 launch): f2b (14464) + W transpose (4096) + rk (1024)
  PrepPtrs P;
  P.q = (const float4*)q; P.k = (const float4*)k; P.v = (const float4*)v;
  P.pos = (const float4*)pos;
  P.qb = qb; P.kb = kb; P.vb = vb; P.posb = posb;
  P.Wq = Wq; P.Wk = Wk; P.Wv = Wv; P.Wo = Wo; P.rk = rk;
  P.Wqt = Wqt; P.Wkt = Wkt; P.Wvt = Wvt; P.Wot = Wot; P.Rkt = Rkt;
  k_prep<<<dim3(19584), 256, 0, stream>>>(P);

  // fused Q/K/V/PE projections
  ProjPtrs pp;
  pp.A0 = qb;  pp.A1 = kb;  pp.A2 = vb;  pp.A3 = posb;
  pp.B0 = Wqt; pp.B1 = Wkt; pp.B2 = Wvt; pp.B3 = Rkt;
  pp.bias0 = bq; pp.bias1 = bk; pp.bias2 = bv;
  pp.rwb = rwb; pp.rrb = rrb;
  pp.Qw = Qw; pp.Qr = Qr; pp.Kh = Kh; pp.Vt = Vt; pp.PEh = PEh;
  k_gemm_proj<<<dim3(8, 32, 4), 256, 0, stream>>>(pp);

  // fused attention (shared-KV LDS pipeline, no merge)
  k_attn<<<dim3(512), 256, 0, stream>>>(Qw, Qr, Kh, Vt, PEh, attnb);

  // output projection (fp32 out)
  k_gemm_o<<<dim3(8, 32), 256, 0, stream>>>(attnb, Wot, bo, outf);
}

// Round 18
// 236.963 us; speedup vs baseline: 1.1319x; 1.1319x over previous
//
#include <hip/hip_runtime.h>
#include <hip/hip_bf16.h>

typedef __attribute__((ext_vector_type(8))) short bf16x8;
typedef __attribute__((ext_vector_type(4))) float f32x4;
typedef __attribute__((ext_vector_type(16))) float f32x16;
typedef unsigned short u16;
typedef unsigned int u32;

#define DEV static __device__ __forceinline__

DEV u16 f2us(float x) {
  __hip_bfloat16 h = __float2bfloat16(x);
  union { __hip_bfloat16 h; u16 u; } c; c.h = h; return c.u;
}
DEV float us2f(u16 u) {
  union { __hip_bfloat16 h; u16 u; } c; c.u = u;
  return __bfloat162float(c.h);
}
DEV f32x16 mfma32(bf16x8 a, bf16x8 b, f32x16 c) {
  return __builtin_amdgcn_mfma_f32_32x32x16_bf16(a, b, c, 0, 0, 0);
}
// pack two f32 -> u32 of two bf16 (RNE)
DEV u32 pkbf(float a, float b) {
  return (u32)f2us(a) | ((u32)f2us(b) << 16);
}
// async global->LDS, 16B per lane
DEV void gl16(const u16* g, u16* l) {
  __builtin_amdgcn_global_load_lds(
      (const __attribute__((address_space(1))) unsigned int*)(g),
      (__attribute__((address_space(3))) unsigned int*)(l), 16, 0, 0);
}

// ---------------- problem constants ----------------
// B=2, L=2048, D=1024, H=16, DH=64, P=L+1=2049
constexpr int PE_ROWS = 2144;   // 2048 + 96 band pad (max row read = 2143)
constexpr int PE_M    = 2176;   // 17 * 128 (GEMM M for PE)
constexpr float QSCALE = 0.125f; // folded softmax scale (dh^-0.5)

// ---------------- workspace layout (bytes) ----------------
constexpr size_t SZ_QKV  = (size_t)4096 * 1024 * 2;
constexpr size_t SZ_W    = (size_t)1024 * 1024 * 2;
constexpr size_t SZ_POSB = (size_t)PE_M * 1024 * 2;
constexpr size_t OFF_QB   = 0;
constexpr size_t OFF_KB   = OFF_QB  + SZ_QKV;
constexpr size_t OFF_VB   = OFF_KB  + SZ_QKV;
constexpr size_t OFF_WQT  = OFF_VB  + SZ_QKV;
constexpr size_t OFF_WKT  = OFF_WQT + SZ_W;
constexpr size_t OFF_WVT  = OFF_WKT + SZ_W;
constexpr size_t OFF_WOT  = OFF_WVT + SZ_W;
constexpr size_t OFF_RKT  = OFF_WOT + SZ_W;
constexpr size_t OFF_POSB = OFF_RKT + SZ_W;
constexpr size_t OFF_QW   = OFF_POSB + SZ_POSB;
constexpr size_t OFF_QR   = OFF_QW  + SZ_QKV;
constexpr size_t OFF_KH   = OFF_QR  + SZ_QKV;
constexpr size_t OFF_VT   = OFF_KH  + SZ_QKV;
constexpr size_t OFF_PEH  = OFF_VT  + SZ_QKV;
constexpr size_t OFF_ATTNB = OFF_QB;  // alias: qb dead after Q-projection GEMM

// ---------------- fused prep kernel (f2b + W transpose + rk transpose) -------
struct PrepPtrs {
  const float4 *q, *k, *v, *pos;
  u16 *qb, *kb, *vb, *posb;
  const float *Wq, *Wk, *Wv, *Wo, *rk;
  u16 *Wqt, *Wkt, *Wvt, *Wot, *Rkt;
};

__global__ __launch_bounds__(256)
void k_prep(PrepPtrs P)
{
  __shared__ float t[32][33];
  const int bid = blockIdx.x;
  if (bid < 14464) {
    // fp32 -> bf16: q/k/v 4096 blocks each, pos 2176 (zero-fill tail)
    const float4* src; u16* dst; int i, n4in, n4tot;
    if (bid < 4096)       { src = P.q;   dst = P.qb;   i = bid * 256 + threadIdx.x;           n4in = 1048576; n4tot = 1048576; }
    else if (bid < 8192)  { src = P.k;   dst = P.kb;   i = (bid - 4096) * 256 + threadIdx.x;  n4in = 1048576; n4tot = 1048576; }
    else if (bid < 12288) { src = P.v;   dst = P.vb;   i = (bid - 8192) * 256 + threadIdx.x;  n4in = 1048576; n4tot = 1048576; }
    else                  { src = P.pos; dst = P.posb; i = (bid - 12288) * 256 + threadIdx.x; n4in = 524544;  n4tot = 557056; }
    if (i >= n4tot) return;
    float4 val;
    if (i < n4in) val = src[i];
    else { val.x = val.y = val.z = val.w = 0.f; }
    ushort4 o;
    o.x = f2us(val.x); o.y = f2us(val.y); o.z = f2us(val.z); o.w = f2us(val.w);
    *reinterpret_cast<ushort4*>(dst + (size_t)i * 4) = o;
    return;
  }
  const int tx = threadIdx.x & 31, ty = threadIdx.x >> 5;
  if (bid < 18560) {
    // W [1024][1024] -> Wt (transposed bf16); 1024 tiles per matrix
    const int tt = bid - 14464;
    const int z = tt >> 10, rr = tt & 1023;
    const float* in = (z == 0) ? P.Wq : (z == 1) ? P.Wk : (z == 2) ? P.Wv : P.Wo;
    u16* out = (z == 0) ? P.Wqt : (z == 1) ? P.Wkt : (z == 2) ? P.Wvt : P.Wot;
    const int kb0 = (rr & 31) * 32, nb0 = (rr >> 5) * 32;
#pragma unroll
    for (int r = 0; r < 32; r += 8)
      t[ty + r][tx] = in[(size_t)(kb0 + ty + r) * 1024 + nb0 + tx];
    __syncthreads();
#pragma unroll
    for (int r = 0; r < 32; r += 8)
      out[(size_t)(nb0 + ty + r) * 1024 + kb0 + tx] = f2us(t[tx][ty + r]);
    return;
  }
  {
    // r_kernel [16][1024][64] -> Rkt[(h*64+e)][d]
    const int tt = bid - 18560;
    const int e = tt & 1, d = (tt >> 1) & 31, h = tt >> 6;
    const int eb0 = e * 32, db0 = d * 32;
#pragma unroll
    for (int r = 0; r < 32; r += 8)
      t[ty + r][tx] = P.rk[(size_t)h * 65536 + (size_t)(db0 + ty + r) * 64 + eb0 + tx];
    __syncthreads();
#pragma unroll
    for (int r = 0; r < 32; r += 8)
      P.Rkt[(size_t)(h * 64 + eb0 + ty + r) * 1024 + db0 + tx] = f2us(t[tx][ty + r]);
  }
}

// ---------------- fused Q/K/V/PE projection GEMM ----------------
struct ProjPtrs {
  const u16 *A0, *A1, *A2, *A3;
  const u16 *B0, *B1, *B2, *B3;
  const float *bias0, *bias1, *bias2;
  const float *rwb, *rrb;
  u16 *Qw, *Qr, *Kh, *Vt, *PEh;
};

__global__ __launch_bounds__(256)
void k_gemm_proj(ProjPtrs pp)
{
  const int z = blockIdx.z;
  if (z == 3 && blockIdx.y >= PE_M / 128) return;
  const u16* A  = (z == 0) ? pp.A0 : (z == 1) ? pp.A1 : (z == 2) ? pp.A2 : pp.A3;
  const u16* Bt = (z == 0) ? pp.B0 : (z == 1) ? pp.B1 : (z == 2) ? pp.B2 : pp.B3;

  __shared__ __attribute__((aligned(16))) u16 As[128 * 32];
  __shared__ __attribute__((aligned(16))) u16 Bs[128 * 32];
  const int tid  = threadIdx.x;
  const int lane = tid & 63;
  const int wave = tid >> 6;
  const int bm = blockIdx.y * 128;
  const int bn = blockIdx.x * 128;
  const int wr = (wave >> 1) * 64;
  const int wc = (wave & 1) * 64;
  const int fr = lane & 15;
  const int fk = (lane >> 4) * 8;

  f32x4 zero = {0.f, 0.f, 0.f, 0.f};
  f32x4 acc[4][4];
#pragma unroll
  for (int m = 0; m < 4; ++m)
#pragma unroll
    for (int n = 0; n < 4; ++n) acc[m][n] = zero;

  const int cA = wave * 2;
  const u16* gA = A  + (size_t)(bm + cA * 16 + (lane >> 2)) * 1024 + (lane & 3) * 8;
  const u16* gB = Bt + (size_t)(bn + cA * 16 + (lane >> 2)) * 1024 + (lane & 3) * 8;
  u16* lA = As + cA * 512;
  u16* lB = Bs + cA * 512;

  for (int k0 = 0; k0 < 1024; k0 += 32) {
    gl16(gA + k0, lA);
    gl16(gA + 16 * 1024 + k0, lA + 512);
    gl16(gB + k0, lB);
    gl16(gB + 16 * 1024 + k0, lB + 512);
    __syncthreads();
    bf16x8 af[4], bfv[4];
#pragma unroll
    for (int m = 0; m < 4; ++m) af[m]  = *(const bf16x8*)(&As[(wr + m * 16 + fr) * 32 + fk]);
#pragma unroll
    for (int n = 0; n < 4; ++n) bfv[n] = *(const bf16x8*)(&Bs[(wc + n * 16 + fr) * 32 + fk]);
#pragma unroll
    for (int m = 0; m < 4; ++m)
#pragma unroll
      for (int n = 0; n < 4; ++n)
        acc[m][n] = __builtin_amdgcn_mfma_f32_16x16x32_bf16(af[m], bfv[n], acc[m][n], 0, 0, 0);
    __syncthreads();
  }

#pragma unroll
  for (int m = 0; m < 4; ++m)
#pragma unroll
    for (int n = 0; n < 4; ++n)
#pragma unroll
      for (int r = 0; r < 4; ++r) {
        const int grow = bm + wr + m * 16 + (lane >> 4) * 4 + r;
        const int gcol = bn + wc + n * 16 + fr;
        float v = acc[m][n][r];
        const int b_ = grow >> 11, l_ = grow & 2047;
        const int h_ = gcol >> 6,  e_ = gcol & 63;
        if (z == 0) {
          v += pp.bias0[gcol];
          const size_t o = (((size_t)(b_ * 16 + h_) * 2048 + l_) << 6) + e_;
          pp.Qw[o] = f2us((v + pp.rwb[gcol]) * QSCALE);
          pp.Qr[o] = f2us((v + pp.rrb[gcol]) * QSCALE);
        } else if (z == 1) {
          v += pp.bias1[gcol];
          const size_t o = (((size_t)(b_ * 16 + h_) * 2048 + l_) << 6) + e_;
          pp.Kh[o] = f2us(v);
        } else if (z == 2) {
          v += pp.bias2[gcol];
          const size_t o = (((size_t)(b_ * 16 + h_) * 64 + e_) << 11) + l_;
          pp.Vt[o] = f2us(v);
        } else {
          if (grow < PE_ROWS) {
            const size_t o = ((size_t)h_ * PE_ROWS + grow) * 64 + e_;
            pp.PEh[o] = f2us(v);
          }
        }
      }
}

// ---------------- output projection GEMM (fp32 out, 64x128 tiles) ------------
// grid dim3(8, 64) = 512 blocks (2/CU; the 128x128 version was 1/CU and
// grid-starved). Per wave: 32x64 = acc[2][4]. LDS 12 KB.
__global__ __launch_bounds__(256)
void k_gemm_o(const u16* __restrict__ A, const u16* __restrict__ Bt,
              const float* __restrict__ bias, float* __restrict__ outf)
{
  __shared__ __attribute__((aligned(16))) u16 As[64 * 32];
  __shared__ __attribute__((aligned(16))) u16 Bs[128 * 32];
  const int tid  = threadIdx.x;
  const int lane = tid & 63;
  const int wave = tid >> 6;
  const int bm = blockIdx.y * 64;
  const int bn = blockIdx.x * 128;
  const int wr = (wave >> 1) * 32;
  const int wc = (wave & 1) * 64;
  const int fr = lane & 15;
  const int fk = (lane >> 4) * 8;

  f32x4 zero = {0.f, 0.f, 0.f, 0.f};
  f32x4 acc[2][4];
#pragma unroll
  for (int m = 0; m < 2; ++m)
#pragma unroll
    for (int n = 0; n < 4; ++n) acc[m][n] = zero;

  // staging: wave w stages A rows [w*16, w*16+16), B rows [w*32, w*32+32)
  const u16* gA = A  + (size_t)(bm + wave * 16 + (lane >> 2)) * 1024 + (lane & 3) * 8;
  const u16* gB = Bt + (size_t)(bn + wave * 32 + (lane >> 2)) * 1024 + (lane & 3) * 8;
  u16* lA = As + wave * 512;
  u16* lB = Bs + wave * 1024;

  for (int k0 = 0; k0 < 1024; k0 += 32) {
    gl16(gA + k0, lA);
    gl16(gB + k0, lB);
    gl16(gB + 16 * 1024 + k0, lB + 512);
    __syncthreads();
    bf16x8 af[2], bfv[4];
#pragma unroll
    for (int m = 0; m < 2; ++m) af[m]  = *(const bf16x8*)(&As[(wr + m * 16 + fr) * 32 + fk]);
#pragma unroll
    for (int n = 0; n < 4; ++n) bfv[n] = *(const bf16x8*)(&Bs[(wc + n * 16 + fr) * 32 + fk]);
#pragma unroll
    for (int m = 0; m < 2; ++m)
#pragma unroll
      for (int n = 0; n < 4; ++n)
        acc[m][n] = __builtin_amdgcn_mfma_f32_16x16x32_bf16(af[m], bfv[n], acc[m][n], 0, 0, 0);
    __syncthreads();
  }

#pragma unroll
  for (int m = 0; m < 2; ++m)
#pragma unroll
    for (int n = 0; n < 4; ++n)
#pragma unroll
      for (int r = 0; r < 4; ++r) {
        const int grow = bm + wr + m * 16 + (lane >> 4) * 4 + r;
        const int gcol = bn + wc + n * 16 + fr;
        outf[(size_t)grow * 1024 + gcol] = acc[m][n][r] + bias[gcol];
      }
}

// ---------------- fused rel-position causal attention ------------------------
// EXACT r16 body (best-known-good: 129.5 us, replay-stable). grid 1024: block
// = tile pair {p, 63-p}; 4 waves split pooled 33 kv-steps (9/8/8/8);
// half-step register discipline; step-scoped Q fragments; (256,4).

// V loads + PV update for one 32-kv half (uses c0h_, l31, hi, Oc0, Oc1, V_h)
#define PV_HALF(WARR)                                                          \
  {                                                                            \
    _Pragma("unroll")                                                          \
    for (int kvs = 0; kvs < 2; ++kvs) {                                        \
      u32 snd0 = hi ? WARR[4 * kvs]     : WARR[4 * kvs + 2];                   \
      u32 snd1 = hi ? WARR[4 * kvs + 1] : WARR[4 * kvs + 3];                   \
      u32 r0 = (u32)__shfl_xor((int)snd0, 32);                                 \
      u32 r1 = (u32)__shfl_xor((int)snd1, 32);                                 \
      union { u32 u[4]; bf16x8 v; } pf;                                        \
      pf.u[0] = hi ? r0 : WARR[4 * kvs];                                       \
      pf.u[1] = hi ? r1 : WARR[4 * kvs + 1];                                   \
      pf.u[2] = hi ? WARR[4 * kvs + 2] : r0;                                   \
      pf.u[3] = hi ? WARR[4 * kvs + 3] : r1;                                   \
      bf16x8 v0_ = *(const bf16x8*)(V_h + (size_t)l31 * 2048 + c0h_            \
                                    + kvs * 16 + hi * 8);                      \
      bf16x8 v1_ = *(const bf16x8*)(V_h + (size_t)(32 + l31) * 2048 + c0h_     \
                                    + kvs * 16 + hi * 8);                      \
      Oc0 = mfma32(v0_, pf.v, Oc0);                                            \
      Oc1 = mfma32(v1_, pf.v, Oc1);                                            \
    }                                                                          \
  }

// one 32-kv half at tile origin q0v; KT in {0,1}; c0_ = step base.
#define ATTN_HALF(q0v, c0_, KT)                                                \
  {                                                                            \
    const int c0h_ = (c0_) + (KT) * 32;                                        \
    f32x16 sv_ = {};                                                           \
    {                                                                          \
      bf16x8 qwf_[4], kf_[4];                                                  \
      _Pragma("unroll")                                                        \
      for (int kk = 0; kk < 4; ++kk) {                                         \
        qwf_[kk] = *(const bf16x8*)(Qw_h + (size_t)((q0v) + l31) * 64          \
                                    + kk * 16 + hi * 8);                       \
        kf_[kk] = *(const bf16x8*)(K_h + (size_t)(c0h_ + l31) * 64 + kk * 16   \
                                   + hi * 8);                                  \
      }                                                                        \
      _Pragma("unroll")                                                        \
      for (int kk = 0; kk < 4; ++kk) sv_ = mfma32(kf_[kk], qwf_[kk], sv_);     \
    }                                                                          \
    _Pragma("unroll")                                                          \
    for (int r = 0; r < 16; ++r) {                                             \
      const int pat = (r & 3) + 8 * (r >> 2) + 4 * hi;                         \
      float x = sv_[r] + us2f(Ew[l31][(KT) * 32 + pat + 31 - l31]);            \
      if (c0h_ + pat > (q0v) + l31) x = -1e30f;                                \
      sv_[r] = x;                                                              \
    }                                                                          \
    float mx_ = sv_[0];                                                        \
    _Pragma("unroll")                                                          \
    for (int r = 1; r < 16; ++r) mx_ = fmaxf(mx_, sv_[r]);                     \
    mx_ = fmaxf(mx_, __shfl_xor(mx_, 32));                                     \
    const float mn_ = fmaxf(mrun, mx_);                                        \
    const float al_ = __expf(mrun - mn_);                                      \
    mrun = mn_;                                                                \
    float rsum_ = 0.f;                                                         \
    u32 wa_[8];                                                                \
    _Pragma("unroll")                                                          \
    for (int g8 = 0; g8 < 8; ++g8) {                                           \
      float pa_ = __expf(sv_[2 * g8] - mn_);                                   \
      float pb_ = __expf(sv_[2 * g8 + 1] - mn_);                               \
      u16 ua_ = f2us(pa_), ub_ = f2us(pb_);                                    \
      rsum_ += us2f(ua_) + us2f(ub_);                                          \
      wa_[g8] = (u32)ua_ | ((u32)ub_ << 16);                                   \
    }                                                                          \
    ls = ls * al_ + rsum_ + __shfl_xor(rsum_, 32);                             \
    Oc0 *= al_;                                                                \
    Oc1 *= al_;                                                                \
    PV_HALF(wa_)                                                               \
  }

// one 64-kv step: E band (3 tiles, qrf_ step-scoped), then two 32-kv halves
#define ATTN_STEP(q0v, stv)                                                    \
  {                                                                            \
    const int c0_ = (stv) * 64;                                                \
    const int Jb_ = 2048 + c0_ - (q0v) - 31;                                   \
    {                                                                          \
      bf16x8 qrf_[4];                                                          \
      _Pragma("unroll")                                                        \
      for (int kk = 0; kk < 4; ++kk)                                           \
        qrf_[kk] = *(const bf16x8*)(Qr_h + (size_t)((q0v) + l31) * 64          \
                                    + kk * 16 + hi * 8);                       \
      _Pragma("unroll")                                                        \
      for (int tau = 0; tau < 3; ++tau) {                                      \
        f32x16 e_ = {};                                                        \
        {                                                                      \
          bf16x8 pe_[4];                                                       \
          _Pragma("unroll")                                                    \
          for (int kk = 0; kk < 4; ++kk)                                       \
            pe_[kk] = *(const bf16x8*)(PE_h + (size_t)(Jb_ + tau * 32 + l31)   \
                                       * 64 + kk * 16 + hi * 8);               \
          _Pragma("unroll")                                                    \
          for (int kk = 0; kk < 4; ++kk) e_ = mfma32(pe_[kk], qrf_[kk], e_);   \
        }                                                                      \
        _Pragma("unroll")                                                      \
        for (int g4 = 0; g4 < 4; ++g4) {                                       \
          uint2 w2_;                                                           \
          w2_.x = pkbf(e_[4 * g4 + 0], e_[4 * g4 + 1]);                        \
          w2_.y = pkbf(e_[4 * g4 + 2], e_[4 * g4 + 3]);                        \
          *(uint2*)(&Ew[l31][tau * 32 + 8 * g4 + 4 * hi]) = w2_;               \
        }                                                                      \
      }                                                                        \
    }                                                                          \
    ATTN_HALF(q0v, c0_, 0)                                                     \
    ATTN_HALF(q0v, c0_, 1)                                                     \
  }

// Obuf round: Obuf = Obuf*PRE + Oc*SCL  (PRE=0 -> fresh write)
#define OBROUND(PRE, SCL)                                                      \
  {                                                                            \
    _Pragma("unroll")                                                          \
    for (int g4 = 0; g4 < 4; ++g4) {                                           \
      float* pb0 = &Obuf[l31][8 * g4 + 4 * hi];                                \
      float* pb1 = &Obuf[l31][32 + 8 * g4 + 4 * hi];                           \
      float2 a0 = *(float2*)pb0,       a1 = *(float2*)(pb0 + 2);               \
      float2 b0 = *(float2*)pb1,       b1 = *(float2*)(pb1 + 2);               \
      a0.x = a0.x * (PRE) + Oc0[4 * g4 + 0] * (SCL);                           \
      a0.y = a0.y * (PRE) + Oc0[4 * g4 + 1] * (SCL);                           \
      a1.x = a1.x * (PRE) + Oc0[4 * g4 + 2] * (SCL);                           \
      a1.y = a1.y * (PRE) + Oc0[4 * g4 + 3] * (SCL);                           \
      b0.x = b0.x * (PRE) + Oc1[4 * g4 + 0] * (SCL);                           \
      b0.y = b0.y * (PRE) + Oc1[4 * g4 + 1] * (SCL);                           \
      b1.x = b1.x * (PRE) + Oc1[4 * g4 + 2] * (SCL);                           \
      b1.y = b1.y * (PRE) + Oc1[4 * g4 + 3] * (SCL);                           \
      *(float2*)pb0 = a0; *(float2*)(pb0 + 2) = a1;                            \
      *(float2*)pb1 = b0; *(float2*)(pb1 + 2) = b1;                            \
    }                                                                          \
  }

__global__ __launch_bounds__(256, 4)
void k_attn(const u16* __restrict__ Qw, const u16* __restrict__ Qr,
            const u16* __restrict__ Kh, const u16* __restrict__ Vt,
            const u16* __restrict__ PEh, u16* __restrict__ attnb)
{
  const int bid = blockIdx.x;
  const int xcd = bid & 7, s = bid >> 3;          // XCD-pinned (h,b)
  const int p = s & 31, g = s >> 5;
  const int hb = xcd + 8 * g;
  const int h = hb & 15, b = hb >> 4;
  const int wave = threadIdx.x >> 6, lane = threadIdx.x & 63;
  const int l31 = lane & 31, hi = lane >> 5;

  const int qtL = 63 - p, qtS = p;
  const int q0L = qtL * 32, q0S = qtS * 32;
  const int nstL = qtL / 2 + 1;                    // in [17,32]; nstL+nstS=33

  const u16* Qw_h = Qw + (size_t)hb * (2048 * 64);
  const u16* Qr_h = Qr + (size_t)hb * (2048 * 64);
  const u16* K_h  = Kh + (size_t)hb * (2048 * 64);
  const u16* V_h  = Vt + (size_t)hb * (64 * 2048);
  const u16* PE_h = PEh + (size_t)h * (PE_ROWS * 64);

  __shared__ __attribute__((aligned(16))) u16 Elds_all[4][32][100];
  __shared__ float Obuf[32][66];
  __shared__ float mlb[2][4][2][32];
  u16 (*Ew)[100] = Elds_all[wave];

  // pooled ranges: wave0 [0,9), wave1 [9,17), wave2 [17,25), wave3 [25,33)
  const int lo  = wave ? 9 + 8 * (wave - 1) : 0;
  const int hiE = lo + (wave ? 8 : 9);
  const int la0 = lo;
  const int la1 = hiE < nstL ? hiE : nstL;
  const int lb0 = lo > nstL ? lo : nstL;
  const int lb1 = hiE;
  const bool hasL = la1 > la0;
  const bool hasS = lb1 > lb0;
  const bool crossing = hasL && hasS;

  const f32x16 vzero = {};
  f32x16 Oc0 = {}, Oc1 = {};
  float mrun = -1e30f, ls = 0.f;

  if (hasL) {
    for (int st = la0; st < la1; ++st) ATTN_STEP(q0L, st)
  }
  if (crossing) {
    // park L partial (unscaled) in Obuf; record its stats; reset regs for S
    OBROUND(0.f, 1.f)
    if (hi == 0) { mlb[0][wave][0][l31] = mrun; mlb[0][wave][1][l31] = ls; }
    Oc0 = vzero; Oc1 = vzero; mrun = -1e30f; ls = 0.f;
  }
  if (hasS) {
    for (int st = lb0 - nstL; st < lb1 - nstL; ++st) ATTN_STEP(q0S, st)
  }

  // record stats (crossing wave already wrote its L entry)
  if (hi == 0) {
    if (crossing) {
      mlb[1][wave][0][l31] = mrun; mlb[1][wave][1][l31] = ls;
    } else if (hasL) {
      mlb[0][wave][0][l31] = mrun;  mlb[0][wave][1][l31] = ls;
      mlb[1][wave][0][l31] = -1e30f; mlb[1][wave][1][l31] = 0.f;
    } else {
      mlb[1][wave][0][l31] = mrun;  mlb[1][wave][1][l31] = ls;
      mlb[0][wave][0][l31] = -1e30f; mlb[0][wave][1][l31] = 0.f;
    }
  }
  __syncthreads();

  // ================= merge =================
  const bool cwExists = (nstL != 17) && (nstL != 25);
  const int  cw = (nstL < 25) ? 2 : 3;

  // ---- tile L ----
  const float mstL = fmaxf(fmaxf(mlb[0][0][0][l31], mlb[0][1][0][l31]),
                           fmaxf(mlb[0][2][0][l31], mlb[0][3][0][l31]));
  if (wave == 0) {            // always pure-L; rescales park (or inits)
    const float preL = cwExists ? __expf(mlb[0][cw][0][l31] - mstL) : 0.f;
    const float scl = __expf(mrun - mstL);
    OBROUND(preL, scl)
  }
  __syncthreads();
  if (wave == 1) {            // always pure-L
    const float scl = __expf(mrun - mstL);
    OBROUND(1.f, scl)
  }
  __syncthreads();
  if (wave == 2 && hasL && !crossing) {   // pure-L only when nstL >= 25
    const float scl = __expf(mrun - mstL);
    OBROUND(1.f, scl)
  }
  __syncthreads();
  if (wave == 0) {            // finalize L
    float lst = 0.f;
#pragma unroll
    for (int w = 0; w < 4; ++w)
      lst += mlb[0][w][1][l31] * __expf(mlb[0][w][0][l31] - mstL);
    const float inv = 1.f / lst;
    const size_t orow = ((size_t)(b * 2048 + q0L + l31)) * 1024 + h * 64 + hi * 32;
#pragma unroll
    for (int j4 = 0; j4 < 32; j4 += 4) {
      float2 t0 = *(float2*)&Obuf[l31][hi * 32 + j4];
      float2 t1 = *(float2*)&Obuf[l31][hi * 32 + j4 + 2];
      ushort4 st;
      st.x = f2us(t0.x * inv); st.y = f2us(t0.y * inv);
      st.z = f2us(t1.x * inv); st.w = f2us(t1.y * inv);
      *(ushort4*)(attnb + orow + j4) = st;
    }
  }
  __syncthreads();

  // ---- tile S (contributors: w2 iff nstL<25, w3 always) ----
  const float mstS = fmaxf(mlb[1][2][0][l31], mlb[1][3][0][l31]);
  if (wave == 2 && hasS) {    // first S writer when nstL < 25
    const float scl = __expf(mrun - mstS);
    OBROUND(0.f, scl)
  }
  __syncthreads();
  if (wave == 3) {            // always has S
    const float scl = __expf(mrun - mstS);
    const float pre = (nstL < 25) ? 1.f : 0.f;
    OBROUND(pre, scl)
  }
  __syncthreads();
  if (wave == 1) {            // finalize S
    float lst = mlb[1][2][1][l31] * __expf(mlb[1][2][0][l31] - mstS)
              + mlb[1][3][1][l31] * __expf(mlb[1][3][0][l31] - mstS);
    const float inv = 1.f / lst;
    const size_t orow = ((size_t)(b * 2048 + q0S + l31)) * 1024 + h * 64 + hi * 32;
#pragma unroll
    for (int j4 = 0; j4 < 32; j4 += 4) {
      float2 t0 = *(float2*)&Obuf[l31][hi * 32 + j4];
      float2 t1 = *(float2*)&Obuf[l31][hi * 32 + j4 + 2];
      ushort4 st;
      st.x = f2us(t0.x * inv); st.y = f2us(t0.y * inv);
      st.z = f2us(t1.x * inv); st.w = f2us(t1.y * inv);
      *(ushort4*)(attnb + orow + j4) = st;
    }
  }
}

// ---------------- launch ----------------
extern "C" void kernel_launch(void* const* d_in, const int* in_sizes, int n_in,
                              void* d_out, int out_size, void* d_ws, size_t ws_size,
                              hipStream_t stream)
{
  const float* q   = (const float*)d_in[0];
  const float* k   = (const float*)d_in[1];
  const float* v   = (const float*)d_in[2];
  const float* pos = (const float*)d_in[3];
  const float* Wq  = (const float*)d_in[4];
  const float* bq  = (const float*)d_in[5];
  const float* Wk  = (const float*)d_in[6];
  const float* bk  = (const float*)d_in[7];
  const float* Wv  = (const float*)d_in[8];
  const float* bv  = (const float*)d_in[9];
  const float* Wo  = (const float*)d_in[10];
  const float* bo  = (const float*)d_in[11];
  const float* rwb = (const float*)d_in[12];
  const float* rrb = (const float*)d_in[13];
  const float* rk  = (const float*)d_in[14];

  char* ws = (char*)d_ws;
  u16* qb    = (u16*)(ws + OFF_QB);
  u16* kb    = (u16*)(ws + OFF_KB);
  u16* vb    = (u16*)(ws + OFF_VB);
  u16* Wqt   = (u16*)(ws + OFF_WQT);
  u16* Wkt   = (u16*)(ws + OFF_WKT);
  u16* Wvt   = (u16*)(ws + OFF_WVT);
  u16* Wot   = (u16*)(ws + OFF_WOT);
  u16* Rkt   = (u16*)(ws + OFF_RKT);
  u16* posb  = (u16*)(ws + OFF_POSB);
  u16* Qw    = (u16*)(ws + OFF_QW);
  u16* Qr    = (u16*)(ws + OFF_QR);
  u16* Kh    = (u16*)(ws + OFF_KH);
  u16* Vt    = (u16*)(ws + OFF_VT);
  u16* PEh   = (u16*)(ws + OFF_PEH);
  u16* attnb = (u16*)(ws + OFF_ATTNB);
  float* outf = (float*)d_out;

  // fused prep (1 launch): f2b (14464) + W transpose (4096) + rk (1024)
  PrepPtrs P;
  P.q = (const float4*)q; P.k = (const float4*)k; P.v = (const float4*)v;
  P.pos = (const float4*)pos;
  P.qb = qb; P.kb = kb; P.vb = vb; P.posb = posb;
  P.Wq = Wq; P.Wk = Wk; P.Wv = Wv; P.Wo = Wo; P.rk = rk;
  P.Wqt = Wqt; P.Wkt = Wkt; P.Wvt = Wvt; P.Wot = Wot; P.Rkt = Rkt;
  k_prep<<<dim3(19584), 256, 0, stream>>>(P);

  // fused Q/K/V/PE projections
  ProjPtrs pp;
  pp.A0 = qb;  pp.A1 = kb;  pp.A2 = vb;  pp.A3 = posb;
  pp.B0 = Wqt; pp.B1 = Wkt; pp.B2 = Wvt; pp.B3 = Rkt;
  pp.bias0 = bq; pp.bias1 = bk; pp.bias2 = bv;
  pp.rwb = rwb; pp.rrb = rrb;
  pp.Qw = Qw; pp.Qr = Qr; pp.Kh = Kh; pp.Vt = Vt; pp.PEh = PEh;
  k_gemm_proj<<<dim3(8, 32, 4), 256, 0, stream>>>(pp);

  // fused attention (r16 best-known-good body)
  k_attn<<<dim3(1024), 256, 0, stream>>>(Qw, Qr, Kh, Vt, PEh, attnb);

  // output projection (fp32 out, 64x128 tiles, 512 blocks)
  k_gemm_o<<<dim3(8, 64), 256, 0, stream>>>(attnb, Wot, bo, outf);
}

// Round 19
// 233.054 us; speedup vs baseline: 1.1509x; 1.0168x over previous
//
#include <hip/hip_runtime.h>
#include <hip/hip_bf16.h>

typedef __attribute__((ext_vector_type(8))) short bf16x8;
typedef __attribute__((ext_vector_type(4))) float f32x4;
typedef __attribute__((ext_vector_type(16))) float f32x16;
typedef unsigned short u16;
typedef unsigned int u32;

#define DEV static __device__ __forceinline__

DEV u16 f2us(float x) {
  __hip_bfloat16 h = __float2bfloat16(x);
  union { __hip_bfloat16 h; u16 u; } c; c.h = h; return c.u;
}
DEV float us2f(u16 u) {
  union { __hip_bfloat16 h; u16 u; } c; c.u = u;
  return __bfloat162float(c.h);
}
DEV f32x16 mfma32(bf16x8 a, bf16x8 b, f32x16 c) {
  return __builtin_amdgcn_mfma_f32_32x32x16_bf16(a, b, c, 0, 0, 0);
}
// pack two f32 -> u32 of two bf16 (RNE)
DEV u32 pkbf(float a, float b) {
  return (u32)f2us(a) | ((u32)f2us(b) << 16);
}
// async global->LDS, 16B per lane
DEV void gl16(const u16* g, u16* l) {
  __builtin_amdgcn_global_load_lds(
      (const __attribute__((address_space(1))) unsigned int*)(g),
      (__attribute__((address_space(3))) unsigned int*)(l), 16, 0, 0);
}

// ---------------- problem constants ----------------
// B=2, L=2048, D=1024, H=16, DH=64, P=L+1=2049
constexpr int PE_ROWS = 2144;   // 2048 + 96 band pad (max row read = 2143)
constexpr int PE_M    = 2176;   // 17 * 128 (GEMM M for PE)
constexpr float QSCALE = 0.125f; // folded softmax scale (dh^-0.5)

// ---------------- workspace layout (bytes) ----------------
constexpr size_t SZ_QKV  = (size_t)4096 * 1024 * 2;
constexpr size_t SZ_W    = (size_t)1024 * 1024 * 2;
constexpr size_t SZ_POSB = (size_t)PE_M * 1024 * 2;
constexpr size_t OFF_QB   = 0;
constexpr size_t OFF_KB   = OFF_QB  + SZ_QKV;
constexpr size_t OFF_VB   = OFF_KB  + SZ_QKV;
constexpr size_t OFF_WQT  = OFF_VB  + SZ_QKV;
constexpr size_t OFF_WKT  = OFF_WQT + SZ_W;
constexpr size_t OFF_WVT  = OFF_WKT + SZ_W;
constexpr size_t OFF_WOT  = OFF_WVT + SZ_W;
constexpr size_t OFF_RKT  = OFF_WOT + SZ_W;
constexpr size_t OFF_POSB = OFF_RKT + SZ_W;
constexpr size_t OFF_QW   = OFF_POSB + SZ_POSB;
constexpr size_t OFF_QR   = OFF_QW  + SZ_QKV;
constexpr size_t OFF_KH   = OFF_QR  + SZ_QKV;
constexpr size_t OFF_VT   = OFF_KH  + SZ_QKV;
constexpr size_t OFF_PEH  = OFF_VT  + SZ_QKV;
constexpr size_t OFF_ATTNB = OFF_QB;  // alias: qb dead after Q-projection GEMM

// ---------------- fused prep kernel (f2b + W transpose + rk transpose) -------
struct PrepPtrs {
  const float4 *q, *k, *v, *pos;
  u16 *qb, *kb, *vb, *posb;
  const float *Wq, *Wk, *Wv, *Wo, *rk;
  u16 *Wqt, *Wkt, *Wvt, *Wot, *Rkt;
};

__global__ __launch_bounds__(256)
void k_prep(PrepPtrs P)
{
  __shared__ float t[32][33];
  const int bid = blockIdx.x;
  if (bid < 14464) {
    // fp32 -> bf16: q/k/v 4096 blocks each, pos 2176 (zero-fill tail)
    const float4* src; u16* dst; int i, n4in, n4tot;
    if (bid < 4096)       { src = P.q;   dst = P.qb;   i = bid * 256 + threadIdx.x;           n4in = 1048576; n4tot = 1048576; }
    else if (bid < 8192)  { src = P.k;   dst = P.kb;   i = (bid - 4096) * 256 + threadIdx.x;  n4in = 1048576; n4tot = 1048576; }
    else if (bid < 12288) { src = P.v;   dst = P.vb;   i = (bid - 8192) * 256 + threadIdx.x;  n4in = 1048576; n4tot = 1048576; }
    else                  { src = P.pos; dst = P.posb; i = (bid - 12288) * 256 + threadIdx.x; n4in = 524544;  n4tot = 557056; }
    if (i >= n4tot) return;
    float4 val;
    if (i < n4in) val = src[i];
    else { val.x = val.y = val.z = val.w = 0.f; }
    ushort4 o;
    o.x = f2us(val.x); o.y = f2us(val.y); o.z = f2us(val.z); o.w = f2us(val.w);
    *reinterpret_cast<ushort4*>(dst + (size_t)i * 4) = o;
    return;
  }
  const int tx = threadIdx.x & 31, ty = threadIdx.x >> 5;
  if (bid < 18560) {
    // W [1024][1024] -> Wt (transposed bf16); 1024 tiles per matrix
    const int tt = bid - 14464;
    const int z = tt >> 10, rr = tt & 1023;
    const float* in = (z == 0) ? P.Wq : (z == 1) ? P.Wk : (z == 2) ? P.Wv : P.Wo;
    u16* out = (z == 0) ? P.Wqt : (z == 1) ? P.Wkt : (z == 2) ? P.Wvt : P.Wot;
    const int kb0 = (rr & 31) * 32, nb0 = (rr >> 5) * 32;
#pragma unroll
    for (int r = 0; r < 32; r += 8)
      t[ty + r][tx] = in[(size_t)(kb0 + ty + r) * 1024 + nb0 + tx];
    __syncthreads();
#pragma unroll
    for (int r = 0; r < 32; r += 8)
      out[(size_t)(nb0 + ty + r) * 1024 + kb0 + tx] = f2us(t[tx][ty + r]);
    return;
  }
  {
    // r_kernel [16][1024][64] -> Rkt[(h*64+e)][d]
    const int tt = bid - 18560;
    const int e = tt & 1, d = (tt >> 1) & 31, h = tt >> 6;
    const int eb0 = e * 32, db0 = d * 32;
#pragma unroll
    for (int r = 0; r < 32; r += 8)
      t[ty + r][tx] = P.rk[(size_t)h * 65536 + (size_t)(db0 + ty + r) * 64 + eb0 + tx];
    __syncthreads();
#pragma unroll
    for (int r = 0; r < 32; r += 8)
      P.Rkt[(size_t)(h * 64 + eb0 + ty + r) * 1024 + db0 + tx] = f2us(t[tx][ty + r]);
  }
}

// ---------------- fused Q/K/V/PE projection GEMM ----------------
// grid dim3(32, 8, 4): bm from blockIdx.x so blocks sharing an A-panel
// co-locate on one XCD (bid&7 == x&7) -> A fetched once per panel; B panels
// replicated per-XCD (cheap: B is 2 MB).
struct ProjPtrs {
  const u16 *A0, *A1, *A2, *A3;
  const u16 *B0, *B1, *B2, *B3;
  const float *bias0, *bias1, *bias2;
  const float *rwb, *rrb;
  u16 *Qw, *Qr, *Kh, *Vt, *PEh;
};

__global__ __launch_bounds__(256)
void k_gemm_proj(ProjPtrs pp)
{
  const int z = blockIdx.z;
  if (z == 3 && blockIdx.x >= PE_M / 128) return;
  const u16* A  = (z == 0) ? pp.A0 : (z == 1) ? pp.A1 : (z == 2) ? pp.A2 : pp.A3;
  const u16* Bt = (z == 0) ? pp.B0 : (z == 1) ? pp.B1 : (z == 2) ? pp.B2 : pp.B3;

  __shared__ __attribute__((aligned(16))) u16 As[128 * 32];
  __shared__ __attribute__((aligned(16))) u16 Bs[128 * 32];
  const int tid  = threadIdx.x;
  const int lane = tid & 63;
  const int wave = tid >> 6;
  const int bm = blockIdx.x * 128;
  const int bn = blockIdx.y * 128;
  const int wr = (wave >> 1) * 64;
  const int wc = (wave & 1) * 64;
  const int fr = lane & 15;
  const int fk = (lane >> 4) * 8;

  f32x4 zero = {0.f, 0.f, 0.f, 0.f};
  f32x4 acc[4][4];
#pragma unroll
  for (int m = 0; m < 4; ++m)
#pragma unroll
    for (int n = 0; n < 4; ++n) acc[m][n] = zero;

  const int cA = wave * 2;
  const u16* gA = A  + (size_t)(bm + cA * 16 + (lane >> 2)) * 1024 + (lane & 3) * 8;
  const u16* gB = Bt + (size_t)(bn + cA * 16 + (lane >> 2)) * 1024 + (lane & 3) * 8;
  u16* lA = As + cA * 512;
  u16* lB = Bs + cA * 512;

  for (int k0 = 0; k0 < 1024; k0 += 32) {
    gl16(gA + k0, lA);
    gl16(gA + 16 * 1024 + k0, lA + 512);
    gl16(gB + k0, lB);
    gl16(gB + 16 * 1024 + k0, lB + 512);
    __syncthreads();
    bf16x8 af[4], bfv[4];
#pragma unroll
    for (int m = 0; m < 4; ++m) af[m]  = *(const bf16x8*)(&As[(wr + m * 16 + fr) * 32 + fk]);
#pragma unroll
    for (int n = 0; n < 4; ++n) bfv[n] = *(const bf16x8*)(&Bs[(wc + n * 16 + fr) * 32 + fk]);
#pragma unroll
    for (int m = 0; m < 4; ++m)
#pragma unroll
      for (int n = 0; n < 4; ++n)
        acc[m][n] = __builtin_amdgcn_mfma_f32_16x16x32_bf16(af[m], bfv[n], acc[m][n], 0, 0, 0);
    __syncthreads();
  }

#pragma unroll
  for (int m = 0; m < 4; ++m)
#pragma unroll
    for (int n = 0; n < 4; ++n)
#pragma unroll
      for (int r = 0; r < 4; ++r) {
        const int grow = bm + wr + m * 16 + (lane >> 4) * 4 + r;
        const int gcol = bn + wc + n * 16 + fr;
        float v = acc[m][n][r];
        const int b_ = grow >> 11, l_ = grow & 2047;
        const int h_ = gcol >> 6,  e_ = gcol & 63;
        if (z == 0) {
          v += pp.bias0[gcol];
          const size_t o = (((size_t)(b_ * 16 + h_) * 2048 + l_) << 6) + e_;
          pp.Qw[o] = f2us((v + pp.rwb[gcol]) * QSCALE);
          pp.Qr[o] = f2us((v + pp.rrb[gcol]) * QSCALE);
        } else if (z == 1) {
          v += pp.bias1[gcol];
          const size_t o = (((size_t)(b_ * 16 + h_) * 2048 + l_) << 6) + e_;
          pp.Kh[o] = f2us(v);
        } else if (z == 2) {
          v += pp.bias2[gcol];
          const size_t o = (((size_t)(b_ * 16 + h_) * 64 + e_) << 11) + l_;
          pp.Vt[o] = f2us(v);
        } else {
          if (grow < PE_ROWS) {
            const size_t o = ((size_t)h_ * PE_ROWS + grow) * 64 + e_;
            pp.PEh[o] = f2us(v);
          }
        }
      }
}

// ---------------- output projection GEMM (fp32 out, 64x128 tiles) ------------
// grid dim3(64, 8): bm from blockIdx.x -> A-panel sharers co-locate per XCD.
__global__ __launch_bounds__(256)
void k_gemm_o(const u16* __restrict__ A, const u16* __restrict__ Bt,
              const float* __restrict__ bias, float* __restrict__ outf)
{
  __shared__ __attribute__((aligned(16))) u16 As[64 * 32];
  __shared__ __attribute__((aligned(16))) u16 Bs[128 * 32];
  const int tid  = threadIdx.x;
  const int lane = tid & 63;
  const int wave = tid >> 6;
  const int bm = blockIdx.x * 64;
  const int bn = blockIdx.y * 128;
  const int wr = (wave >> 1) * 32;
  const int wc = (wave & 1) * 64;
  const int fr = lane & 15;
  const int fk = (lane >> 4) * 8;

  f32x4 zero = {0.f, 0.f, 0.f, 0.f};
  f32x4 acc[2][4];
#pragma unroll
  for (int m = 0; m < 2; ++m)
#pragma unroll
    for (int n = 0; n < 4; ++n) acc[m][n] = zero;

  // staging: wave w stages A rows [w*16, w*16+16), B rows [w*32, w*32+32)
  const u16* gA = A  + (size_t)(bm + wave * 16 + (lane >> 2)) * 1024 + (lane & 3) * 8;
  const u16* gB = Bt + (size_t)(bn + wave * 32 + (lane >> 2)) * 1024 + (lane & 3) * 8;
  u16* lA = As + wave * 512;
  u16* lB = Bs + wave * 1024;

  for (int k0 = 0; k0 < 1024; k0 += 32) {
    gl16(gA + k0, lA);
    gl16(gB + k0, lB);
    gl16(gB + 16 * 1024 + k0, lB + 512);
    __syncthreads();
    bf16x8 af[2], bfv[4];
#pragma unroll
    for (int m = 0; m < 2; ++m) af[m]  = *(const bf16x8*)(&As[(wr + m * 16 + fr) * 32 + fk]);
#pragma unroll
    for (int n = 0; n < 4; ++n) bfv[n] = *(const bf16x8*)(&Bs[(wc + n * 16 + fr) * 32 + fk]);
#pragma unroll
    for (int m = 0; m < 2; ++m)
#pragma unroll
      for (int n = 0; n < 4; ++n)
        acc[m][n] = __builtin_amdgcn_mfma_f32_16x16x32_bf16(af[m], bfv[n], acc[m][n], 0, 0, 0);
    __syncthreads();
  }

#pragma unroll
  for (int m = 0; m < 2; ++m)
#pragma unroll
    for (int n = 0; n < 4; ++n)
#pragma unroll
      for (int r = 0; r < 4; ++r) {
        const int grow = bm + wr + m * 16 + (lane >> 4) * 4 + r;
        const int gcol = bn + wc + n * 16 + fr;
        outf[(size_t)grow * 1024 + gcol] = acc[m][n][r] + bias[gcol];
      }
}

// ---------------- fused rel-position causal attention ------------------------
// EXACT r16 body (best-known-good: 129.5 us, replay-stable). grid 1024: block
// = tile pair {p, 63-p}; 4 waves split pooled 33 kv-steps (9/8/8/8);
// half-step register discipline; step-scoped Q fragments; (256,4).

// V loads + PV update for one 32-kv half (uses c0h_, l31, hi, Oc0, Oc1, V_h)
#define PV_HALF(WARR)                                                          \
  {                                                                            \
    _Pragma("unroll")                                                          \
    for (int kvs = 0; kvs < 2; ++kvs) {                                        \
      u32 snd0 = hi ? WARR[4 * kvs]     : WARR[4 * kvs + 2];                   \
      u32 snd1 = hi ? WARR[4 * kvs + 1] : WARR[4 * kvs + 3];                   \
      u32 r0 = (u32)__shfl_xor((int)snd0, 32);                                 \
      u32 r1 = (u32)__shfl_xor((int)snd1, 32);                                 \
      union { u32 u[4]; bf16x8 v; } pf;                                        \
      pf.u[0] = hi ? r0 : WARR[4 * kvs];                                       \
      pf.u[1] = hi ? r1 : WARR[4 * kvs + 1];                                   \
      pf.u[2] = hi ? WARR[4 * kvs + 2] : r0;                                   \
      pf.u[3] = hi ? WARR[4 * kvs + 3] : r1;                                   \
      bf16x8 v0_ = *(const bf16x8*)(V_h + (size_t)l31 * 2048 + c0h_            \
                                    + kvs * 16 + hi * 8);                      \
      bf16x8 v1_ = *(const bf16x8*)(V_h + (size_t)(32 + l31) * 2048 + c0h_     \
                                    + kvs * 16 + hi * 8);                      \
      Oc0 = mfma32(v0_, pf.v, Oc0);                                            \
      Oc1 = mfma32(v1_, pf.v, Oc1);                                            \
    }                                                                          \
  }

// one 32-kv half at tile origin q0v; KT in {0,1}; c0_ = step base.
#define ATTN_HALF(q0v, c0_, KT)                                                \
  {                                                                            \
    const int c0h_ = (c0_) + (KT) * 32;                                        \
    f32x16 sv_ = {};                                                           \
    {                                                                          \
      bf16x8 qwf_[4], kf_[4];                                                  \
      _Pragma("unroll")                                                        \
      for (int kk = 0; kk < 4; ++kk) {                                         \
        qwf_[kk] = *(const bf16x8*)(Qw_h + (size_t)((q0v) + l31) * 64          \
                                    + kk * 16 + hi * 8);                       \
        kf_[kk] = *(const bf16x8*)(K_h + (size_t)(c0h_ + l31) * 64 + kk * 16   \
                                   + hi * 8);                                  \
      }                                                                        \
      _Pragma("unroll")                                                        \
      for (int kk = 0; kk < 4; ++kk) sv_ = mfma32(kf_[kk], qwf_[kk], sv_);     \
    }                                                                          \
    _Pragma("unroll")                                                          \
    for (int r = 0; r < 16; ++r) {                                             \
      const int pat = (r & 3) + 8 * (r >> 2) + 4 * hi;                         \
      float x = sv_[r] + us2f(Ew[l31][(KT) * 32 + pat + 31 - l31]);            \
      if (c0h_ + pat > (q0v) + l31) x = -1e30f;                                \
      sv_[r] = x;                                                              \
    }                                                                          \
    float mx_ = sv_[0];                                                        \
    _Pragma("unroll")                                                          \
    for (int r = 1; r < 16; ++r) mx_ = fmaxf(mx_, sv_[r]);                     \
    mx_ = fmaxf(mx_, __shfl_xor(mx_, 32));                                     \
    const float mn_ = fmaxf(mrun, mx_);                                        \
    const float al_ = __expf(mrun - mn_);                                      \
    mrun = mn_;                                                                \
    float rsum_ = 0.f;                                                         \
    u32 wa_[8];                                                                \
    _Pragma("unroll")                                                          \
    for (int g8 = 0; g8 < 8; ++g8) {                                           \
      float pa_ = __expf(sv_[2 * g8] - mn_);                                   \
      float pb_ = __expf(sv_[2 * g8 + 1] - mn_);                               \
      u16 ua_ = f2us(pa_), ub_ = f2us(pb_);                                    \
      rsum_ += us2f(ua_) + us2f(ub_);                                          \
      wa_[g8] = (u32)ua_ | ((u32)ub_ << 16);                                   \
    }                                                                          \
    ls = ls * al_ + rsum_ + __shfl_xor(rsum_, 32);                             \
    Oc0 *= al_;                                                                \
    Oc1 *= al_;                                                                \
    PV_HALF(wa_)                                                               \
  }

// one 64-kv step: E band (3 tiles, qrf_ step-scoped), then two 32-kv halves
#define ATTN_STEP(q0v, stv)                                                    \
  {                                                                            \
    const int c0_ = (stv) * 64;                                                \
    const int Jb_ = 2048 + c0_ - (q0v) - 31;                                   \
    {                                                                          \
      bf16x8 qrf_[4];                                                          \
      _Pragma("unroll")                                                        \
      for (int kk = 0; kk < 4; ++kk)                                           \
        qrf_[kk] = *(const bf16x8*)(Qr_h + (size_t)((q0v) + l31) * 64          \
                                    + kk * 16 + hi * 8);                       \
      _Pragma("unroll")                                                        \
      for (int tau = 0; tau < 3; ++tau) {                                      \
        f32x16 e_ = {};                                                        \
        {                                                                      \
          bf16x8 pe_[4];                                                       \
          _Pragma("unroll")                                                    \
          for (int kk = 0; kk < 4; ++kk)                                       \
            pe_[kk] = *(const bf16x8*)(PE_h + (size_t)(Jb_ + tau * 32 + l31)   \
                                       * 64 + kk * 16 + hi * 8);               \
          _Pragma("unroll")                                                    \
          for (int kk = 0; kk < 4; ++kk) e_ = mfma32(pe_[kk], qrf_[kk], e_);   \
        }                                                                      \
        _Pragma("unroll")                                                      \
        for (int g4 = 0; g4 < 4; ++g4) {                                       \
          uint2 w2_;                                                           \
          w2_.x = pkbf(e_[4 * g4 + 0], e_[4 * g4 + 1]);                        \
          w2_.y = pkbf(e_[4 * g4 + 2], e_[4 * g4 + 3]);                        \
          *(uint2*)(&Ew[l31][tau * 32 + 8 * g4 + 4 * hi]) = w2_;               \
        }                                                                      \
      }                                                                        \
    }                                                                          \
    ATTN_HALF(q0v, c0_, 0)                                                     \
    ATTN_HALF(q0v, c0_, 1)                                                     \
  }

// Obuf round: Obuf = Obuf*PRE + Oc*SCL  (PRE=0 -> fresh write)
#define OBROUND(PRE, SCL)                                                      \
  {                                                                            \
    _Pragma("unroll")                                                          \
    for (int g4 = 0; g4 < 4; ++g4) {                                           \
      float* pb0 = &Obuf[l31][8 * g4 + 4 * hi];                                \
      float* pb1 = &Obuf[l31][32 + 8 * g4 + 4 * hi];                           \
      float2 a0 = *(float2*)pb0,       a1 = *(float2*)(pb0 + 2);               \
      float2 b0 = *(float2*)pb1,       b1 = *(float2*)(pb1 + 2);               \
      a0.x = a0.x * (PRE) + Oc0[4 * g4 + 0] * (SCL);                           \
      a0.y = a0.y * (PRE) + Oc0[4 * g4 + 1] * (SCL);                           \
      a1.x = a1.x * (PRE) + Oc0[4 * g4 + 2] * (SCL);                           \
      a1.y = a1.y * (PRE) + Oc0[4 * g4 + 3] * (SCL);                           \
      b0.x = b0.x * (PRE) + Oc1[4 * g4 + 0] * (SCL);                           \
      b0.y = b0.y * (PRE) + Oc1[4 * g4 + 1] * (SCL);                           \
      b1.x = b1.x * (PRE) + Oc1[4 * g4 + 2] * (SCL);                           \
      b1.y = b1.y * (PRE) + Oc1[4 * g4 + 3] * (SCL);                           \
      *(float2*)pb0 = a0; *(float2*)(pb0 + 2) = a1;                            \
      *(float2*)pb1 = b0; *(float2*)(pb1 + 2) = b1;                            \
    }                                                                          \
  }

__global__ __launch_bounds__(256, 4)
void k_attn(const u16* __restrict__ Qw, const u16* __restrict__ Qr,
            const u16* __restrict__ Kh, const u16* __restrict__ Vt,
            const u16* __restrict__ PEh, u16* __restrict__ attnb)
{
  const int bid = blockIdx.x;
  const int xcd = bid & 7, s = bid >> 3;          // XCD-pinned (h,b)
  const int p = s & 31, g = s >> 5;
  const int hb = xcd + 8 * g;
  const int h = hb & 15, b = hb >> 4;
  const int wave = threadIdx.x >> 6, lane = threadIdx.x & 63;
  const int l31 = lane & 31, hi = lane >> 5;

  const int qtL = 63 - p, qtS = p;
  const int q0L = qtL * 32, q0S = qtS * 32;
  const int nstL = qtL / 2 + 1;                    // in [17,32]; nstL+nstS=33

  const u16* Qw_h = Qw + (size_t)hb * (2048 * 64);
  const u16* Qr_h = Qr + (size_t)hb * (2048 * 64);
  const u16* K_h  = Kh + (size_t)hb * (2048 * 64);
  const u16* V_h  = Vt + (size_t)hb * (64 * 2048);
  const u16* PE_h = PEh + (size_t)h * (PE_ROWS * 64);

  __shared__ __attribute__((aligned(16))) u16 Elds_all[4][32][100];
  __shared__ float Obuf[32][66];
  __shared__ float mlb[2][4][2][32];
  u16 (*Ew)[100] = Elds_all[wave];

  // pooled ranges: wave0 [0,9), wave1 [9,17), wave2 [17,25), wave3 [25,33)
  const int lo  = wave ? 9 + 8 * (wave - 1) : 0;
  const int hiE = lo + (wave ? 8 : 9);
  const int la0 = lo;
  const int la1 = hiE < nstL ? hiE : nstL;
  const int lb0 = lo > nstL ? lo : nstL;
  const int lb1 = hiE;
  const bool hasL = la1 > la0;
  const bool hasS = lb1 > lb0;
  const bool crossing = hasL && hasS;

  const f32x16 vzero = {};
  f32x16 Oc0 = {}, Oc1 = {};
  float mrun = -1e30f, ls = 0.f;

  if (hasL) {
    for (int st = la0; st < la1; ++st) ATTN_STEP(q0L, st)
  }
  if (crossing) {
    // park L partial (unscaled) in Obuf; record its stats; reset regs for S
    OBROUND(0.f, 1.f)
    if (hi == 0) { mlb[0][wave][0][l31] = mrun; mlb[0][wave][1][l31] = ls; }
    Oc0 = vzero; Oc1 = vzero; mrun = -1e30f; ls = 0.f;
  }
  if (hasS) {
    for (int st = lb0 - nstL; st < lb1 - nstL; ++st) ATTN_STEP(q0S, st)
  }

  // record stats (crossing wave already wrote its L entry)
  if (hi == 0) {
    if (crossing) {
      mlb[1][wave][0][l31] = mrun; mlb[1][wave][1][l31] = ls;
    } else if (hasL) {
      mlb[0][wave][0][l31] = mrun;  mlb[0][wave][1][l31] = ls;
      mlb[1][wave][0][l31] = -1e30f; mlb[1][wave][1][l31] = 0.f;
    } else {
      mlb[1][wave][0][l31] = mrun;  mlb[1][wave][1][l31] = ls;
      mlb[0][wave][0][l31] = -1e30f; mlb[0][wave][1][l31] = 0.f;
    }
  }
  __syncthreads();

  // ================= merge =================
  const bool cwExists = (nstL != 17) && (nstL != 25);
  const int  cw = (nstL < 25) ? 2 : 3;

  // ---- tile L ----
  const float mstL = fmaxf(fmaxf(mlb[0][0][0][l31], mlb[0][1][0][l31]),
                           fmaxf(mlb[0][2][0][l31], mlb[0][3][0][l31]));
  if (wave == 0) {            // always pure-L; rescales park (or inits)
    const float preL = cwExists ? __expf(mlb[0][cw][0][l31] - mstL) : 0.f;
    const float scl = __expf(mrun - mstL);
    OBROUND(preL, scl)
  }
  __syncthreads();
  if (wave == 1) {            // always pure-L
    const float scl = __expf(mrun - mstL);
    OBROUND(1.f, scl)
  }
  __syncthreads();
  if (wave == 2 && hasL && !crossing) {   // pure-L only when nstL >= 25
    const float scl = __expf(mrun - mstL);
    OBROUND(1.f, scl)
  }
  __syncthreads();
  if (wave == 0) {            // finalize L
    float lst = 0.f;
#pragma unroll
    for (int w = 0; w < 4; ++w)
      lst += mlb[0][w][1][l31] * __expf(mlb[0][w][0][l31] - mstL);
    const float inv = 1.f / lst;
    const size_t orow = ((size_t)(b * 2048 + q0L + l31)) * 1024 + h * 64 + hi * 32;
#pragma unroll
    for (int j4 = 0; j4 < 32; j4 += 4) {
      float2 t0 = *(float2*)&Obuf[l31][hi * 32 + j4];
      float2 t1 = *(float2*)&Obuf[l31][hi * 32 + j4 + 2];
      ushort4 st;
      st.x = f2us(t0.x * inv); st.y = f2us(t0.y * inv);
      st.z = f2us(t1.x * inv); st.w = f2us(t1.y * inv);
      *(ushort4*)(attnb + orow + j4) = st;
    }
  }
  __syncthreads();

  // ---- tile S (contributors: w2 iff nstL<25, w3 always) ----
  const float mstS = fmaxf(mlb[1][2][0][l31], mlb[1][3][0][l31]);
  if (wave == 2 && hasS) {    // first S writer when nstL < 25
    const float scl = __expf(mrun - mstS);
    OBROUND(0.f, scl)
  }
  __syncthreads();
  if (wave == 3) {            // always has S
    const float scl = __expf(mrun - mstS);
    const float pre = (nstL < 25) ? 1.f : 0.f;
    OBROUND(pre, scl)
  }
  __syncthreads();
  if (wave == 1) {            // finalize S
    float lst = mlb[1][2][1][l31] * __expf(mlb[1][2][0][l31] - mstS)
              + mlb[1][3][1][l31] * __expf(mlb[1][3][0][l31] - mstS);
    const float inv = 1.f / lst;
    const size_t orow = ((size_t)(b * 2048 + q0S + l31)) * 1024 + h * 64 + hi * 32;
#pragma unroll
    for (int j4 = 0; j4 < 32; j4 += 4) {
      float2 t0 = *(float2*)&Obuf[l31][hi * 32 + j4];
      float2 t1 = *(float2*)&Obuf[l31][hi * 32 + j4 + 2];
      ushort4 st;
      st.x = f2us(t0.x * inv); st.y = f2us(t0.y * inv);
      st.z = f2us(t1.x * inv); st.w = f2us(t1.y * inv);
      *(ushort4*)(attnb + orow + j4) = st;
    }
  }
}

// ---------------- launch ----------------
extern "C" void kernel_launch(void* const* d_in, const int* in_sizes, int n_in,
                              void* d_out, int out_size, void* d_ws, size_t ws_size,
                              hipStream_t stream)
{
  const float* q   = (const float*)d_in[0];
  const float* k   = (const float*)d_in[1];
  const float* v   = (const float*)d_in[2];
  const float* pos = (const float*)d_in[3];
  const float* Wq  = (const float*)d_in[4];
  const float* bq  = (const float*)d_in[5];
  const float* Wk  = (const float*)d_in[6];
  const float* bk  = (const float*)d_in[7];
  const float* Wv  = (const float*)d_in[8];
  const float* bv  = (const float*)d_in[9];
  const float* Wo  = (const float*)d_in[10];
  const float* bo  = (const float*)d_in[11];
  const float* rwb = (const float*)d_in[12];
  const float* rrb = (const float*)d_in[13];
  const float* rk  = (const float*)d_in[14];

  char* ws = (char*)d_ws;
  u16* qb    = (u16*)(ws + OFF_QB);
  u16* kb    = (u16*)(ws + OFF_KB);
  u16* vb    = (u16*)(ws + OFF_VB);
  u16* Wqt   = (u16*)(ws + OFF_WQT);
  u16* Wkt   = (u16*)(ws + OFF_WKT);
  u16* Wvt   = (u16*)(ws + OFF_WVT);
  u16* Wot   = (u16*)(ws + OFF_WOT);
  u16* Rkt   = (u16*)(ws + OFF_RKT);
  u16* posb  = (u16*)(ws + OFF_POSB);
  u16* Qw    = (u16*)(ws + OFF_QW);
  u16* Qr    = (u16*)(ws + OFF_QR);
  u16* Kh    = (u16*)(ws + OFF_KH);
  u16* Vt    = (u16*)(ws + OFF_VT);
  u16* PEh   = (u16*)(ws + OFF_PEH);
  u16* attnb = (u16*)(ws + OFF_ATTNB);
  float* outf = (float*)d_out;

  // fused prep (1 launch): f2b (14464) + W transpose (4096) + rk (1024)
  PrepPtrs P;
  P.q = (const float4*)q; P.k = (const float4*)k; P.v = (const float4*)v;
  P.pos = (const float4*)pos;
  P.qb = qb; P.kb = kb; P.vb = vb; P.posb = posb;
  P.Wq = Wq; P.Wk = Wk; P.Wv = Wv; P.Wo = Wo; P.rk = rk;
  P.Wqt = Wqt; P.Wkt = Wkt; P.Wvt = Wvt; P.Wot = Wot; P.Rkt = Rkt;
  k_prep<<<dim3(19584), 256, 0, stream>>>(P);

  // fused Q/K/V/PE projections (A-panel XCD co-location)
  ProjPtrs pp;
  pp.A0 = qb;  pp.A1 = kb;  pp.A2 = vb;  pp.A3 = posb;
  pp.B0 = Wqt; pp.B1 = Wkt; pp.B2 = Wvt; pp.B3 = Rkt;
  pp.bias0 = bq; pp.bias1 = bk; pp.bias2 = bv;
  pp.rwb = rwb; pp.rrb = rrb;
  pp.Qw = Qw; pp.Qr = Qr; pp.Kh = Kh; pp.Vt = Vt; pp.PEh = PEh;
  k_gemm_proj<<<dim3(32, 8, 4), 256, 0, stream>>>(pp);

  // fused attention (r16 best-known-good body)
  k_attn<<<dim3(1024), 256, 0, stream>>>(Qw, Qr, Kh, Vt, PEh, attnb);

  // output projection (fp32 out, 64x128 tiles, A-panel XCD co-location)
  k_gemm_o<<<dim3(64, 8), 256, 0, stream>>>(attnb, Wot, bo, outf);
}